// Round 2
// baseline (1677.456 us; speedup 1.0000x reference)
//
#include <hip/hip_runtime.h>

#define N_NODES 32768
#define DEG 16
#define IN_F 128
#define HIDF 256
#define N_GRAPHS 256
#define NPG 128
#define OUT_F 16

typedef unsigned short u16;
typedef unsigned int u32;
typedef __bf16 bf16x8 __attribute__((ext_vector_type(8)));
typedef float f32x4 __attribute__((ext_vector_type(4)));
typedef u16 u16x4 __attribute__((ext_vector_type(4)));
typedef u16 u16x8 __attribute__((ext_vector_type(8)));

__device__ __forceinline__ u16 f2bf(float f) {
  union { float f; unsigned u; } v; v.f = f;
  return (u16)((v.u + 0x7FFFu + ((v.u >> 16) & 1u)) >> 16);
}
__device__ __forceinline__ float bf2f(u16 b) {
  union { unsigned u; float f; } v; v.u = ((unsigned)b) << 16;
  return v.f;
}
__device__ __forceinline__ float sigm(float x) { return 1.0f / (1.0f + __expf(-x)); }
__device__ __forceinline__ float tanhfast(float x) {
  float e = __expf(2.0f * x);
  return (e - 1.0f) / (e + 1.0f);
}

template <int F> struct GTsel;
template <> struct GTsel<128> { using T = u16x4; };  // 8B per-lane gather
template <> struct GTsel<256> { using T = u16x8; };  // 16B per-lane gather

// ---- prep kernels -------------------------------------------------------

__global__ void k_prep_x(const float* __restrict__ x, u16* __restrict__ out, int n4) {
  int i = blockIdx.x * blockDim.x + threadIdx.x;
  if (i < n4) {
    float4 v = ((const float4*)x)[i];
    ushort4 o;
    o.x = f2bf(v.x); o.y = f2bf(v.y); o.z = f2bf(v.z); o.w = f2bf(v.w);
    ((ushort4*)out)[i] = o;
  }
}

// Permuted LSTM weight layout (vector-gather friendly):
//   np = w*(F/2) + l16*(F/32) + pass*(F/64) + ntp
// so each recur lane's per-step XW gather is ONE contiguous F/32-u16 load
// covering both passes. gate map: pass0 {gp0:i(0), gp1:g(2)},
// pass1 {gp0:f(1), gp1:o(3)}; within-gate feature = w*(F/8) + l16*FT + ft.
__global__ void k_prep_perm(const float* __restrict__ Wi, const float* __restrict__ Wh,
                            const float* __restrict__ bi, const float* __restrict__ bh,
                            u16* __restrict__ Bxw, u16* __restrict__ Bhh,
                            float* __restrict__ biasw, int F) {
  int FT = F >> 7;
  int W2 = F >> 1, L2v = F >> 5, P2 = F >> 6;
  int total = 4 * F * F;
  for (int idx = blockIdx.x * blockDim.x + threadIdx.x; idx < total;
       idx += gridDim.x * blockDim.x) {
    int np = idx / F;
    int k = idx % F;
    int w = np / W2;      int rem = np % W2;
    int l16 = rem / L2v;  int r2 = rem % L2v;
    int pass = r2 / P2;   int ntp = r2 % P2;
    int gp = ntp / FT;    int ft = ntp % FT;
    int gate = (pass == 0) ? (gp == 0 ? 0 : 2) : (gp == 0 ? 1 : 3);
    int orig = gate * F + w * (F >> 3) + l16 * FT + ft;
    Bxw[idx] = f2bf(Wi[orig * F + k]);
    Bhh[idx] = f2bf(Wh[orig * F + k]);
    if (k == 0) biasw[np] = bi[orig] + bh[orig];
  }
}

__global__ void k_prep_cast(const float* __restrict__ Ws, const float* __restrict__ Wn,
                            u16* __restrict__ Bs, u16* __restrict__ Bn, int n) {
  int i = blockIdx.x * blockDim.x + threadIdx.x;
  if (i < n) { Bs[i] = f2bf(Ws[i]); Bn[i] = f2bf(Wn[i]); }
}

// ---- dense GEMM: C[M][NC] = bf16(A[M][K] @ B[NC][K]^T + bias) ------------
template <int K, int NC>
__launch_bounds__(256, 4)
__global__ void k_gemm(const u16* __restrict__ A, const u16* __restrict__ B,
                       const float* __restrict__ bias, u16* __restrict__ C) {
  constexpr int ROWB = 2 * K;
  __shared__ u16 lds[64 * K];
  char* ldsb = (char*)lds;
  const int tid = threadIdx.x;
  const int w = tid >> 6;
  const int lane = tid & 63;
  const int l16 = lane & 15, lq = lane >> 4;
  const int row0 = blockIdx.x * 64;
  const int col0 = blockIdx.y * 128;

  constexpr int CH = K / 8;
  constexpr int RPI = 256 / CH;
#pragma unroll
  for (int it = 0; it < 64 / RPI; ++it) {
    int r = tid / CH + it * RPI;
    int ch = tid % CH;
    bf16x8 v = *(const bf16x8*)(A + (size_t)(row0 + r) * K + ch * 8);
    int bo = r * ROWB + ((ch * 16) ^ ((r & 7) << 4));
    *(bf16x8*)(ldsb + bo) = v;
  }
  __syncthreads();

  f32x4 acc[4][2];
#pragma unroll
  for (int mt = 0; mt < 4; ++mt)
#pragma unroll
    for (int nt = 0; nt < 2; ++nt)
#pragma unroll
      for (int j = 0; j < 4; ++j) acc[mt][nt][j] = 0.f;

  for (int ks = 0; ks < K / 32; ++ks) {
    bf16x8 a[4];
#pragma unroll
    for (int mt = 0; mt < 4; ++mt) {
      int r = mt * 16 + l16;
      int bo = r * ROWB + (((ks * 32 + lq * 8) * 2) ^ ((r & 7) << 4));
      a[mt] = *(const bf16x8*)(ldsb + bo);
    }
#pragma unroll
    for (int nt = 0; nt < 2; ++nt) {
      int coln = col0 + w * 32 + nt * 16 + l16;
      bf16x8 b = *(const bf16x8*)(B + (size_t)coln * K + ks * 32 + lq * 8);
#pragma unroll
      for (int mt = 0; mt < 4; ++mt)
        acc[mt][nt] = __builtin_amdgcn_mfma_f32_16x16x32_bf16(a[mt], b, acc[mt][nt], 0, 0, 0);
    }
  }
#pragma unroll
  for (int mt = 0; mt < 4; ++mt)
#pragma unroll
    for (int nt = 0; nt < 2; ++nt) {
      int coln = col0 + w * 32 + nt * 16 + l16;
      float bb = bias[coln];
#pragma unroll
      for (int j = 0; j < 4; ++j) {
        int r = row0 + mt * 16 + lq * 4 + j;
        C[(size_t)r * NC + coln] = f2bf(acc[mt][nt][j] + bb);
      }
    }
}

// ---- recurrent LSTM aggregation + combine --------------------------------
// 8 waves x 32 nodes. XW gathers issued one step EARLY:
//  - F=256: via global_load_lds (per-lane global src, lane-linear LDS dest),
//    zero VGPR cost; single 64KB stage buffer, per-wave 8KB slices (no
//    cross-wave sharing -> no extra barriers). End-of-step __syncthreads
//    drains vmcnt, so staged data is ready next step.
//  - F=128: register next-buffer (small pressure, no spill).
// One barrier per step.
template <int F>
__launch_bounds__(512, 2)
__global__ void k_recur(const u16* __restrict__ XW,   // [N][4F] permuted, bias folded
                        const u16* __restrict__ XS,   // [N][HIDF] self-part + b
                        const int* __restrict__ nbr,  // [N][DEG]
                        const u16* __restrict__ Bh,   // [4F][F] permuted rows
                        const u16* __restrict__ Bn,   // [HIDF][F]
                        u16* __restrict__ out) {      // [N][HIDF]
  constexpr int FT = F / 128;
  constexpr int NTP = F / 64;   // per-pass ntp count
  constexpr int KS = F / 32;
  constexpr int ROWB = 2 * F;
  constexpr bool STG = (F == 256);
  using GT = typename GTsel<F>::T;

  __shared__ __align__(16) u16 hbuf[2][32 * F];
  __shared__ __align__(16) int snbrT[DEG * 32];
  __shared__ __align__(16) char stagebuf[STG ? 65536 : 16];

  const int tid = threadIdx.x;
  const int w = tid >> 6;
  const int lane = tid & 63;
  const int l16 = lane & 15, lq = lane >> 4;
  const int node_base = blockIdx.x * 32;

  // stage transposed neighbor table: snbrT[t][node]
  for (int i = tid; i < 32 * DEG; i += 512) {
    int r = i / DEG, t = i % DEG;
    snbrT[t * 32 + r] = nbr[(node_base + r) * DEG + t];
  }
  for (int i = tid; i < 32 * F / 8; i += 512) ((int4*)hbuf[0])[i] = make_int4(0, 0, 0, 0);

  float c[2][FT][4];
#pragma unroll
  for (int mt = 0; mt < 2; ++mt)
#pragma unroll
    for (int ft = 0; ft < FT; ++ft)
#pragma unroll
      for (int j = 0; j < 4; ++j) c[mt][ft][j] = 0.f;

  __syncthreads();

  const int xwoff = w * (F / 2) + l16 * (F / 32);
  const u16* bhb = Bh + (size_t)xwoff * F + lq * 8;
  char* swave = stagebuf + w * 8192;

  GT xwn[2][4];  // F=128 reg path: next-step buffer

  auto issue = [&](int t) {
#pragma unroll
    for (int mt = 0; mt < 2; ++mt) {
      int4 nb = *(const int4*)&snbrT[t * 32 + mt * 16 + lq * 4];
      const u16* s0 = XW + (size_t)nb.x * (4 * F) + xwoff;
      const u16* s1 = XW + (size_t)nb.y * (4 * F) + xwoff;
      const u16* s2 = XW + (size_t)nb.z * (4 * F) + xwoff;
      const u16* s3 = XW + (size_t)nb.w * (4 * F) + xwoff;
      if constexpr (STG) {
        char* d = swave + mt * 4096;
        __builtin_amdgcn_global_load_lds((const __attribute__((address_space(1))) unsigned*)s0,
                                         (__attribute__((address_space(3))) unsigned*)(d + 0), 16, 0, 0);
        __builtin_amdgcn_global_load_lds((const __attribute__((address_space(1))) unsigned*)s1,
                                         (__attribute__((address_space(3))) unsigned*)(d + 1024), 16, 0, 0);
        __builtin_amdgcn_global_load_lds((const __attribute__((address_space(1))) unsigned*)s2,
                                         (__attribute__((address_space(3))) unsigned*)(d + 2048), 16, 0, 0);
        __builtin_amdgcn_global_load_lds((const __attribute__((address_space(1))) unsigned*)s3,
                                         (__attribute__((address_space(3))) unsigned*)(d + 3072), 16, 0, 0);
      } else {
        xwn[mt][0] = *(const GT*)s0;
        xwn[mt][1] = *(const GT*)s1;
        xwn[mt][2] = *(const GT*)s2;
        xwn[mt][3] = *(const GT*)s3;
      }
    }
  };

  issue(0);

#pragma unroll 1
  for (int t = 0; t < DEG; ++t) {
    const int p = t & 1;
    const char* hrd = (const char*)hbuf[p];
    char* hwr = (char*)hbuf[p ^ 1];

    // ---- consume staged XW for this step ----
    GT xwf[2][4];
    if constexpr (STG) {
      // t=0: DMA issued with no intervening barrier -> drain. Steady state:
      // end-of-step __syncthreads already drained vmcnt, this is free.
      asm volatile("s_waitcnt vmcnt(0)" ::: "memory");
#pragma unroll
      for (int mt = 0; mt < 2; ++mt)
#pragma unroll
        for (int j = 0; j < 4; ++j)
          xwf[mt][j] = *(const GT*)(swave + (mt * 4 + j) * 1024 + lane * 16);
      // stage reads must complete before next issue overwrites the buffer
      asm volatile("s_waitcnt lgkmcnt(0)" ::: "memory");
      __builtin_amdgcn_sched_barrier(0);
    } else {
#pragma unroll
      for (int mt = 0; mt < 2; ++mt)
#pragma unroll
        for (int j = 0; j < 4; ++j) xwf[mt][j] = xwn[mt][j];
    }
    if (t + 1 < DEG) issue(t + 1);  // prefetch next step under this step's compute

    float ig[2][FT][4];
    f32x4 acc[2][NTP];

    // ---- pass 0: gates i, g ----
#pragma unroll
    for (int mt = 0; mt < 2; ++mt)
#pragma unroll
      for (int ntp = 0; ntp < NTP; ++ntp)
#pragma unroll
        for (int j = 0; j < 4; ++j) acc[mt][ntp][j] = bf2f(xwf[mt][j][ntp]);

#pragma unroll 2
    for (int ks = 0; ks < KS; ++ks) {
      bf16x8 a[2];
#pragma unroll
      for (int mt = 0; mt < 2; ++mt) {
        int r = mt * 16 + l16;
        int bo = r * ROWB + (((ks * 32 + lq * 8) * 2) ^ ((r & 7) << 4));
        a[mt] = *(const bf16x8*)(hrd + bo);
      }
#pragma unroll
      for (int ntp = 0; ntp < NTP; ++ntp) {
        bf16x8 b = *(const bf16x8*)(bhb + (size_t)ntp * F + ks * 32);
        acc[0][ntp] = __builtin_amdgcn_mfma_f32_16x16x32_bf16(a[0], b, acc[0][ntp], 0, 0, 0);
        acc[1][ntp] = __builtin_amdgcn_mfma_f32_16x16x32_bf16(a[1], b, acc[1][ntp], 0, 0, 0);
      }
    }
#pragma unroll
    for (int mt = 0; mt < 2; ++mt)
#pragma unroll
      for (int ft = 0; ft < FT; ++ft)
#pragma unroll
        for (int j = 0; j < 4; ++j)
          ig[mt][ft][j] = sigm(acc[mt][ft][j]) * tanhfast(acc[mt][FT + ft][j]);

    // ---- pass 1: gates f, o ----
#pragma unroll
    for (int mt = 0; mt < 2; ++mt)
#pragma unroll
      for (int ntp = 0; ntp < NTP; ++ntp)
#pragma unroll
        for (int j = 0; j < 4; ++j) acc[mt][ntp][j] = bf2f(xwf[mt][j][NTP + ntp]);

#pragma unroll 2
    for (int ks = 0; ks < KS; ++ks) {
      bf16x8 a[2];
#pragma unroll
      for (int mt = 0; mt < 2; ++mt) {
        int r = mt * 16 + l16;
        int bo = r * ROWB + (((ks * 32 + lq * 8) * 2) ^ ((r & 7) << 4));
        a[mt] = *(const bf16x8*)(hrd + bo);
      }
#pragma unroll
      for (int ntp = 0; ntp < NTP; ++ntp) {
        bf16x8 b = *(const bf16x8*)(bhb + (size_t)(NTP + ntp) * F + ks * 32);
        acc[0][ntp] = __builtin_amdgcn_mfma_f32_16x16x32_bf16(a[0], b, acc[0][ntp], 0, 0, 0);
        acc[1][ntp] = __builtin_amdgcn_mfma_f32_16x16x32_bf16(a[1], b, acc[1][ntp], 0, 0, 0);
      }
    }
#pragma unroll
    for (int mt = 0; mt < 2; ++mt)
#pragma unroll
      for (int j = 0; j < 4; ++j) {
        int m = mt * 16 + lq * 4 + j;
        if constexpr (FT == 1) {
          float cn = sigm(acc[mt][0][j]) * c[mt][0][j] + ig[mt][0][j];
          c[mt][0][j] = cn;
          float hn = sigm(acc[mt][1][j]) * tanhfast(cn);
          int fe = w * (F / 8) + l16;
          int bo = m * ROWB + ((fe * 2) ^ ((m & 7) << 4));
          *(u16*)(hwr + bo) = f2bf(hn);
        } else {
          float cn0 = sigm(acc[mt][0][j]) * c[mt][0][j] + ig[mt][0][j];
          float cn1 = sigm(acc[mt][1][j]) * c[mt][1][j] + ig[mt][1][j];
          c[mt][0][j] = cn0;
          c[mt][1][j] = cn1;
          float hn0 = sigm(acc[mt][FT][j]) * tanhfast(cn0);
          float hn1 = sigm(acc[mt][FT + 1][j]) * tanhfast(cn1);
          int fe = w * (F / 8) + l16 * 2;
          int bo = m * ROWB + ((fe * 2) ^ ((m & 7) << 4));
          *(u32*)(hwr + bo) = (u32)f2bf(hn0) | ((u32)f2bf(hn1) << 16);
        }
      }
    __syncthreads();
  }

  // combine: out = relu(XS[node] + h16 @ Bn^T)   (DEG even -> h16 in hbuf[0])
  const char* hrd = (const char*)hbuf[0];
  f32x4 acc2[2][2];
#pragma unroll
  for (int mt = 0; mt < 2; ++mt)
#pragma unroll
    for (int nt = 0; nt < 2; ++nt) {
      int coln = w * 32 + nt * 16 + l16;
      u16 xsu[4];
#pragma unroll
      for (int j = 0; j < 4; ++j)
        xsu[j] = XS[(size_t)(node_base + mt * 16 + lq * 4 + j) * HIDF + coln];
#pragma unroll
      for (int j = 0; j < 4; ++j) acc2[mt][nt][j] = bf2f(xsu[j]);
    }

#pragma unroll 2
  for (int ks = 0; ks < KS; ++ks) {
    bf16x8 a[2];
#pragma unroll
    for (int mt = 0; mt < 2; ++mt) {
      int r = mt * 16 + l16;
      int bo = r * ROWB + (((ks * 32 + lq * 8) * 2) ^ ((r & 7) << 4));
      a[mt] = *(const bf16x8*)(hrd + bo);
    }
#pragma unroll
    for (int nt = 0; nt < 2; ++nt) {
      int coln = w * 32 + nt * 16 + l16;
      bf16x8 b = *(const bf16x8*)(Bn + (size_t)coln * F + ks * 32 + lq * 8);
      acc2[0][nt] = __builtin_amdgcn_mfma_f32_16x16x32_bf16(a[0], b, acc2[0][nt], 0, 0, 0);
      acc2[1][nt] = __builtin_amdgcn_mfma_f32_16x16x32_bf16(a[1], b, acc2[1][nt], 0, 0, 0);
    }
  }
#pragma unroll
  for (int mt = 0; mt < 2; ++mt)
#pragma unroll
    for (int nt = 0; nt < 2; ++nt) {
      int coln = w * 32 + nt * 16 + l16;
#pragma unroll
      for (int j = 0; j < 4; ++j) {
        int m = node_base + mt * 16 + lq * 4 + j;
        out[(size_t)m * HIDF + coln] = f2bf(fmaxf(acc2[mt][nt][j], 0.f));
      }
    }
}

// ---- mean-pool per graph + classifier -----------------------------------
__global__ void k_pool(const u16* __restrict__ h2, const float* __restrict__ Wc,
                       const float* __restrict__ bc, float* __restrict__ out) {
  __shared__ float hg[HIDF];
  int g = blockIdx.x;
  int tid = threadIdx.x;
  float s = 0.0f;
  for (int i = 0; i < NPG; ++i) s += bf2f(h2[(size_t)(g * NPG + i) * HIDF + tid]);
  hg[tid] = s * (1.0f / NPG);
  __syncthreads();
  if (tid < OUT_F) {
    float o = bc[tid];
    for (int fe = 0; fe < HIDF; ++fe) o += hg[fe] * Wc[tid * HIDF + fe];
    out[g * OUT_F + tid] = o;
  }
}

// ---- launch -------------------------------------------------------------
extern "C" void kernel_launch(void* const* d_in, const int* in_sizes, int n_in,
                              void* d_out, int out_size, void* d_ws, size_t ws_size,
                              hipStream_t stream) {
  const float* x   = (const float*)d_in[0];
  const int*   nbr = (const int*)d_in[1];
  const float* Wi1 = (const float*)d_in[2];
  const float* Wh1 = (const float*)d_in[3];
  const float* bi1 = (const float*)d_in[4];
  const float* bh1 = (const float*)d_in[5];
  const float* Ws1 = (const float*)d_in[6];
  const float* Wn1 = (const float*)d_in[7];
  const float* b1  = (const float*)d_in[8];
  const float* Wi2 = (const float*)d_in[9];
  const float* Wh2 = (const float*)d_in[10];
  const float* bi2 = (const float*)d_in[11];
  const float* bh2 = (const float*)d_in[12];
  const float* Ws2 = (const float*)d_in[13];
  const float* Wn2 = (const float*)d_in[14];
  const float* b2  = (const float*)d_in[15];
  const float* Wc  = (const float*)d_in[16];
  const float* bc  = (const float*)d_in[17];
  float* out = (float*)d_out;

  char* ws = (char*)d_ws;
  const size_t MB = 1u << 20;
  // lifetimes: x16 dead after XW1/XS1; XW1,XS1 dead after recur1;
  // h1 dead after XW2/XS2; so XS2 aliases XS1, h2 aliases XW1.
  u16* x16 = (u16*)(ws + 0);          //  8 MB
  u16* XW1 = (u16*)(ws + 8 * MB);     // 32 MB
  u16* XS1 = (u16*)(ws + 40 * MB);    // 16 MB
  u16* h1  = (u16*)(ws + 56 * MB);    // 16 MB
  u16* XW2 = (u16*)(ws + 72 * MB);    // 64 MB
  u16* XS2 = (u16*)(ws + 40 * MB);    // alias XS1
  u16* h2  = (u16*)(ws + 8 * MB);     // alias XW1
  char* wr = ws + 136 * MB;
  size_t off = 0;
  auto alloc = [&](size_t bytes) { void* p = wr + off; off += (bytes + 255) & ~(size_t)255; return p; };
  u16*   Bxw1 = (u16*)alloc(512 * 128 * 2);
  u16*   Bh1  = (u16*)alloc(512 * 128 * 2);
  float* bw1  = (float*)alloc(512 * 4);
  u16*   Bs1  = (u16*)alloc(256 * 128 * 2);
  u16*   Bn1  = (u16*)alloc(256 * 128 * 2);
  u16*   Bxw2 = (u16*)alloc(1024 * 256 * 2);
  u16*   Bh2  = (u16*)alloc(1024 * 256 * 2);
  float* bw2  = (float*)alloc(1024 * 4);
  u16*   Bs2  = (u16*)alloc(256 * 256 * 2);
  u16*   Bn2  = (u16*)alloc(256 * 256 * 2);

  k_prep_x<<<dim3(N_NODES * IN_F / 4 / 256), dim3(256), 0, stream>>>(x, x16, N_NODES * IN_F / 4);
  k_prep_perm<<<dim3(256), dim3(256), 0, stream>>>(Wi1, Wh1, bi1, bh1, Bxw1, Bh1, bw1, IN_F);
  k_prep_perm<<<dim3(1024), dim3(256), 0, stream>>>(Wi2, Wh2, bi2, bh2, Bxw2, Bh2, bw2, HIDF);
  k_prep_cast<<<dim3(128), dim3(256), 0, stream>>>(Ws1, Wn1, Bs1, Bn1, 256 * 128);
  k_prep_cast<<<dim3(256), dim3(256), 0, stream>>>(Ws2, Wn2, Bs2, Bn2, 256 * 256);

  k_gemm<128, 512><<<dim3(N_NODES / 64, 4), dim3(256), 0, stream>>>(x16, Bxw1, bw1, XW1);
  k_gemm<128, 256><<<dim3(N_NODES / 64, 2), dim3(256), 0, stream>>>(x16, Bs1, b1, XS1);
  k_recur<IN_F><<<dim3(N_NODES / 32), dim3(512), 0, stream>>>(XW1, XS1, nbr, Bh1, Bn1, h1);
  k_gemm<256, 1024><<<dim3(N_NODES / 64, 8), dim3(256), 0, stream>>>(h1, Bxw2, bw2, XW2);
  k_gemm<256, 256><<<dim3(N_NODES / 64, 2), dim3(256), 0, stream>>>(h1, Bs2, b2, XS2);
  k_recur<HIDF><<<dim3(N_NODES / 32), dim3(512), 0, stream>>>(XW2, XS2, nbr, Bh2, Bn2, h2);

  k_pool<<<dim3(N_GRAPHS), dim3(256), 0, stream>>>(h2, Wc, bc, out);
}

// Round 3
// 1524.126 us; speedup vs baseline: 1.1006x; 1.1006x over previous
//
#include <hip/hip_runtime.h>

#define N_NODES 32768
#define DEG 16
#define IN_F 128
#define HIDF 256
#define N_GRAPHS 256
#define NPG 128
#define OUT_F 16

typedef unsigned short u16;
typedef unsigned int u32;
typedef __bf16 bf16x8 __attribute__((ext_vector_type(8)));
typedef float f32x4 __attribute__((ext_vector_type(4)));
typedef u16 u16x4 __attribute__((ext_vector_type(4)));
typedef u16 u16x8 __attribute__((ext_vector_type(8)));

__device__ __forceinline__ u16 f2bf(float f) {
  union { float f; unsigned u; } v; v.f = f;
  return (u16)((v.u + 0x7FFFu + ((v.u >> 16) & 1u)) >> 16);
}
__device__ __forceinline__ float bf2f(u16 b) {
  union { unsigned u; float f; } v; v.u = ((unsigned)b) << 16;
  return v.f;
}
__device__ __forceinline__ float sigm(float x) { return 1.0f / (1.0f + __expf(-x)); }
__device__ __forceinline__ float tanhfast(float x) {
  float e = __expf(2.0f * x);
  return (e - 1.0f) / (e + 1.0f);
}

template <int F> struct GTsel;
template <> struct GTsel<128> { using T = u16x4; };  // 8B per-lane gather
template <> struct GTsel<256> { using T = u16x8; };  // 16B per-lane gather

// ---- prep kernels -------------------------------------------------------

__global__ void k_prep_x(const float* __restrict__ x, u16* __restrict__ out, int n4) {
  int i = blockIdx.x * blockDim.x + threadIdx.x;
  if (i < n4) {
    float4 v = ((const float4*)x)[i];
    ushort4 o;
    o.x = f2bf(v.x); o.y = f2bf(v.y); o.z = f2bf(v.z); o.w = f2bf(v.w);
    ((ushort4*)out)[i] = o;
  }
}

// Permuted LSTM weight layout (vector-gather friendly):
//   np = w*(F/2) + l16*(F/32) + pass*(F/64) + ntp
// so each recur lane's per-step XW gather is ONE contiguous F/32-u16 load
// covering both passes. gate map: pass0 {gp0:i(0), gp1:g(2)},
// pass1 {gp0:f(1), gp1:o(3)}; within-gate feature = w*(F/8) + l16*FT + ft.
__global__ void k_prep_perm(const float* __restrict__ Wi, const float* __restrict__ Wh,
                            const float* __restrict__ bi, const float* __restrict__ bh,
                            u16* __restrict__ Bxw, u16* __restrict__ Bhh,
                            float* __restrict__ biasw, int F) {
  int FT = F >> 7;
  int W2 = F >> 1, L2v = F >> 5, P2 = F >> 6;
  int total = 4 * F * F;
  for (int idx = blockIdx.x * blockDim.x + threadIdx.x; idx < total;
       idx += gridDim.x * blockDim.x) {
    int np = idx / F;
    int k = idx % F;
    int w = np / W2;      int rem = np % W2;
    int l16 = rem / L2v;  int r2 = rem % L2v;
    int pass = r2 / P2;   int ntp = r2 % P2;
    int gp = ntp / FT;    int ft = ntp % FT;
    int gate = (pass == 0) ? (gp == 0 ? 0 : 2) : (gp == 0 ? 1 : 3);
    int orig = gate * F + w * (F >> 3) + l16 * FT + ft;
    Bxw[idx] = f2bf(Wi[orig * F + k]);
    Bhh[idx] = f2bf(Wh[orig * F + k]);
    if (k == 0) biasw[np] = bi[orig] + bh[orig];
  }
}

__global__ void k_prep_cast(const float* __restrict__ Ws, const float* __restrict__ Wn,
                            u16* __restrict__ Bs, u16* __restrict__ Bn, int n) {
  int i = blockIdx.x * blockDim.x + threadIdx.x;
  if (i < n) { Bs[i] = f2bf(Ws[i]); Bn[i] = f2bf(Wn[i]); }
}

// ---- dense GEMM: C[M][NC] = bf16(A[M][K] @ B[NC][K]^T + bias) ------------
template <int K, int NC>
__launch_bounds__(256, 4)
__global__ void k_gemm(const u16* __restrict__ A, const u16* __restrict__ B,
                       const float* __restrict__ bias, u16* __restrict__ C) {
  constexpr int ROWB = 2 * K;
  __shared__ u16 lds[64 * K];
  char* ldsb = (char*)lds;
  const int tid = threadIdx.x;
  const int w = tid >> 6;
  const int lane = tid & 63;
  const int l16 = lane & 15, lq = lane >> 4;
  const int row0 = blockIdx.x * 64;
  const int col0 = blockIdx.y * 128;

  constexpr int CH = K / 8;
  constexpr int RPI = 256 / CH;
#pragma unroll
  for (int it = 0; it < 64 / RPI; ++it) {
    int r = tid / CH + it * RPI;
    int ch = tid % CH;
    bf16x8 v = *(const bf16x8*)(A + (size_t)(row0 + r) * K + ch * 8);
    int bo = r * ROWB + ((ch * 16) ^ ((r & 7) << 4));
    *(bf16x8*)(ldsb + bo) = v;
  }
  __syncthreads();

  f32x4 acc[4][2];
#pragma unroll
  for (int mt = 0; mt < 4; ++mt)
#pragma unroll
    for (int nt = 0; nt < 2; ++nt)
#pragma unroll
      for (int j = 0; j < 4; ++j) acc[mt][nt][j] = 0.f;

  for (int ks = 0; ks < K / 32; ++ks) {
    bf16x8 a[4];
#pragma unroll
    for (int mt = 0; mt < 4; ++mt) {
      int r = mt * 16 + l16;
      int bo = r * ROWB + (((ks * 32 + lq * 8) * 2) ^ ((r & 7) << 4));
      a[mt] = *(const bf16x8*)(ldsb + bo);
    }
#pragma unroll
    for (int nt = 0; nt < 2; ++nt) {
      int coln = col0 + w * 32 + nt * 16 + l16;
      bf16x8 b = *(const bf16x8*)(B + (size_t)coln * K + ks * 32 + lq * 8);
#pragma unroll
      for (int mt = 0; mt < 4; ++mt)
        acc[mt][nt] = __builtin_amdgcn_mfma_f32_16x16x32_bf16(a[mt], b, acc[mt][nt], 0, 0, 0);
    }
  }
#pragma unroll
  for (int mt = 0; mt < 4; ++mt)
#pragma unroll
    for (int nt = 0; nt < 2; ++nt) {
      int coln = col0 + w * 32 + nt * 16 + l16;
      float bb = bias[coln];
#pragma unroll
      for (int j = 0; j < 4; ++j) {
        int r = row0 + mt * 16 + lq * 4 + j;
        C[(size_t)r * NC + coln] = f2bf(acc[mt][nt][j] + bb);
      }
    }
}

// ---- recurrent LSTM aggregation + combine --------------------------------
// 8 waves x 32 nodes, 2 blocks/CU target (VGPR<=128, LDS ~35KB).
// Key points:
//  - acc starts at 0; the h@Bh MFMA chain has NO dependency on the XW
//    gathers, which are issued at step start and consumed only at gate
//    math (commutative add) -> gather latency hides under the MFMA chain.
//  - t=0: h==0, so the whole MFMA chain + Bh loads are skipped.
//  - KS loop fully unrolled so the scheduler can hoist Bh loads.
//  - One barrier per step.
template <int F>
__launch_bounds__(512, 4)
__global__ void k_recur(const u16* __restrict__ XW,   // [N][4F] permuted, bias folded
                        const u16* __restrict__ XS,   // [N][HIDF] self-part + b
                        const int* __restrict__ nbr,  // [N][DEG]
                        const u16* __restrict__ Bh,   // [4F][F] permuted rows
                        const u16* __restrict__ Bn,   // [HIDF][F]
                        u16* __restrict__ out) {      // [N][HIDF]
  constexpr int FT = F / 128;
  constexpr int NTP = F / 64;   // per-pass ntp count
  constexpr int KS = F / 32;
  constexpr int ROWB = 2 * F;
  using GT = typename GTsel<F>::T;

  __shared__ __align__(16) u16 hbuf[2][32 * F];
  __shared__ __align__(16) int snbrT[DEG * 32];

  const int tid = threadIdx.x;
  const int w = tid >> 6;
  const int lane = tid & 63;
  const int l16 = lane & 15, lq = lane >> 4;
  const int node_base = blockIdx.x * 32;

  // stage transposed neighbor table: snbrT[t][node]
  for (int i = tid; i < 32 * DEG; i += 512) {
    int r = i / DEG, t = i % DEG;
    snbrT[t * 32 + r] = nbr[(node_base + r) * DEG + t];
  }

  float c[2][FT][4];
#pragma unroll
  for (int mt = 0; mt < 2; ++mt)
#pragma unroll
    for (int ft = 0; ft < FT; ++ft)
#pragma unroll
      for (int j = 0; j < 4; ++j) c[mt][ft][j] = 0.f;

  __syncthreads();

  const int xwoff = w * (F / 2) + l16 * (F / 32);
  const u16* bhb = Bh + (size_t)xwoff * F + lq * 8;

#pragma unroll 1
  for (int t = 0; t < DEG; ++t) {
    const char* hrd = (const char*)hbuf[t & 1];
    char* hwr = (char*)hbuf[(t & 1) ^ 1];

    // issue XW gathers FIRST; consumed only at gate math below.
    GT xwf[2][4];
#pragma unroll
    for (int mt = 0; mt < 2; ++mt) {
      int4 nb = *(const int4*)&snbrT[t * 32 + mt * 16 + lq * 4];
      xwf[mt][0] = *(const GT*)(XW + (size_t)nb.x * (4 * F) + xwoff);
      xwf[mt][1] = *(const GT*)(XW + (size_t)nb.y * (4 * F) + xwoff);
      xwf[mt][2] = *(const GT*)(XW + (size_t)nb.z * (4 * F) + xwoff);
      xwf[mt][3] = *(const GT*)(XW + (size_t)nb.w * (4 * F) + xwoff);
    }

    float ig[2][FT][4];
#pragma unroll
    for (int pass = 0; pass < 2; ++pass) {
      f32x4 acc[2][NTP];
#pragma unroll
      for (int mt = 0; mt < 2; ++mt)
#pragma unroll
        for (int ntp = 0; ntp < NTP; ++ntp)
#pragma unroll
          for (int j = 0; j < 4; ++j) acc[mt][ntp][j] = 0.f;

      if (t > 0) {
#pragma unroll
        for (int ks = 0; ks < KS; ++ks) {
          bf16x8 a[2];
#pragma unroll
          for (int mt = 0; mt < 2; ++mt) {
            int r = mt * 16 + l16;
            int bo = r * ROWB + (((ks * 32 + lq * 8) * 2) ^ ((r & 7) << 4));
            a[mt] = *(const bf16x8*)(hrd + bo);
          }
#pragma unroll
          for (int ntp = 0; ntp < NTP; ++ntp) {
            bf16x8 b = *(const bf16x8*)(bhb + (size_t)(pass * NTP + ntp) * F + ks * 32);
            acc[0][ntp] = __builtin_amdgcn_mfma_f32_16x16x32_bf16(a[0], b, acc[0][ntp], 0, 0, 0);
            acc[1][ntp] = __builtin_amdgcn_mfma_f32_16x16x32_bf16(a[1], b, acc[1][ntp], 0, 0, 0);
          }
        }
      }

      if (pass == 0) {
        // gates i (ntp=ft) and g (ntp=FT+ft); XW term added here.
#pragma unroll
        for (int mt = 0; mt < 2; ++mt)
#pragma unroll
          for (int ft = 0; ft < FT; ++ft)
#pragma unroll
            for (int j = 0; j < 4; ++j) {
              float pi = acc[mt][ft][j] + bf2f((u16)xwf[mt][j][ft]);
              float pg = acc[mt][FT + ft][j] + bf2f((u16)xwf[mt][j][FT + ft]);
              ig[mt][ft][j] = sigm(pi) * tanhfast(pg);
            }
      } else {
        // gates f (ntp=ft) and o (ntp=FT+ft); XW elems offset by NTP.
#pragma unroll
        for (int mt = 0; mt < 2; ++mt)
#pragma unroll
          for (int j = 0; j < 4; ++j) {
            int m = mt * 16 + lq * 4 + j;
            if constexpr (FT == 1) {
              float pf = acc[mt][0][j] + bf2f((u16)xwf[mt][j][NTP]);
              float po = acc[mt][1][j] + bf2f((u16)xwf[mt][j][NTP + 1]);
              float cn = sigm(pf) * c[mt][0][j] + ig[mt][0][j];
              c[mt][0][j] = cn;
              float hn = sigm(po) * tanhfast(cn);
              int fe = w * (F / 8) + l16;
              int bo = m * ROWB + ((fe * 2) ^ ((m & 7) << 4));
              *(u16*)(hwr + bo) = f2bf(hn);
            } else {
              float pf0 = acc[mt][0][j] + bf2f((u16)xwf[mt][j][NTP]);
              float pf1 = acc[mt][1][j] + bf2f((u16)xwf[mt][j][NTP + 1]);
              float po0 = acc[mt][FT][j] + bf2f((u16)xwf[mt][j][NTP + FT]);
              float po1 = acc[mt][FT + 1][j] + bf2f((u16)xwf[mt][j][NTP + FT + 1]);
              float cn0 = sigm(pf0) * c[mt][0][j] + ig[mt][0][j];
              float cn1 = sigm(pf1) * c[mt][1][j] + ig[mt][1][j];
              c[mt][0][j] = cn0;
              c[mt][1][j] = cn1;
              float hn0 = sigm(po0) * tanhfast(cn0);
              float hn1 = sigm(po1) * tanhfast(cn1);
              int fe = w * (F / 8) + l16 * 2;
              int bo = m * ROWB + ((fe * 2) ^ ((m & 7) << 4));
              *(u32*)(hwr + bo) = (u32)f2bf(hn0) | ((u32)f2bf(hn1) << 16);
            }
          }
      }
    }
    __syncthreads();
  }

  // combine: out = relu(XS[node] + h16 @ Bn^T)   (DEG even -> h16 in hbuf[0])
  const char* hrd = (const char*)hbuf[0];
  f32x4 acc2[2][2];
#pragma unroll
  for (int mt = 0; mt < 2; ++mt)
#pragma unroll
    for (int nt = 0; nt < 2; ++nt) {
      int coln = w * 32 + nt * 16 + l16;
      u16 xsu[4];
#pragma unroll
      for (int j = 0; j < 4; ++j)
        xsu[j] = XS[(size_t)(node_base + mt * 16 + lq * 4 + j) * HIDF + coln];
#pragma unroll
      for (int j = 0; j < 4; ++j) acc2[mt][nt][j] = bf2f(xsu[j]);
    }

#pragma unroll
  for (int ks = 0; ks < KS; ++ks) {
    bf16x8 a[2];
#pragma unroll
    for (int mt = 0; mt < 2; ++mt) {
      int r = mt * 16 + l16;
      int bo = r * ROWB + (((ks * 32 + lq * 8) * 2) ^ ((r & 7) << 4));
      a[mt] = *(const bf16x8*)(hrd + bo);
    }
#pragma unroll
    for (int nt = 0; nt < 2; ++nt) {
      int coln = w * 32 + nt * 16 + l16;
      bf16x8 b = *(const bf16x8*)(Bn + (size_t)coln * F + ks * 32 + lq * 8);
      acc2[0][nt] = __builtin_amdgcn_mfma_f32_16x16x32_bf16(a[0], b, acc2[0][nt], 0, 0, 0);
      acc2[1][nt] = __builtin_amdgcn_mfma_f32_16x16x32_bf16(a[1], b, acc2[1][nt], 0, 0, 0);
    }
  }
#pragma unroll
  for (int mt = 0; mt < 2; ++mt)
#pragma unroll
    for (int nt = 0; nt < 2; ++nt) {
      int coln = w * 32 + nt * 16 + l16;
#pragma unroll
      for (int j = 0; j < 4; ++j) {
        int m = node_base + mt * 16 + lq * 4 + j;
        out[(size_t)m * HIDF + coln] = f2bf(fmaxf(acc2[mt][nt][j], 0.f));
      }
    }
}

// ---- mean-pool per graph + classifier -----------------------------------
__global__ void k_pool(const u16* __restrict__ h2, const float* __restrict__ Wc,
                       const float* __restrict__ bc, float* __restrict__ out) {
  __shared__ float hg[HIDF];
  int g = blockIdx.x;
  int tid = threadIdx.x;
  float s = 0.0f;
  for (int i = 0; i < NPG; ++i) s += bf2f(h2[(size_t)(g * NPG + i) * HIDF + tid]);
  hg[tid] = s * (1.0f / NPG);
  __syncthreads();
  if (tid < OUT_F) {
    float o = bc[tid];
    for (int fe = 0; fe < HIDF; ++fe) o += hg[fe] * Wc[tid * HIDF + fe];
    out[g * OUT_F + tid] = o;
  }
}

// ---- launch -------------------------------------------------------------
extern "C" void kernel_launch(void* const* d_in, const int* in_sizes, int n_in,
                              void* d_out, int out_size, void* d_ws, size_t ws_size,
                              hipStream_t stream) {
  const float* x   = (const float*)d_in[0];
  const int*   nbr = (const int*)d_in[1];
  const float* Wi1 = (const float*)d_in[2];
  const float* Wh1 = (const float*)d_in[3];
  const float* bi1 = (const float*)d_in[4];
  const float* bh1 = (const float*)d_in[5];
  const float* Ws1 = (const float*)d_in[6];
  const float* Wn1 = (const float*)d_in[7];
  const float* b1  = (const float*)d_in[8];
  const float* Wi2 = (const float*)d_in[9];
  const float* Wh2 = (const float*)d_in[10];
  const float* bi2 = (const float*)d_in[11];
  const float* bh2 = (const float*)d_in[12];
  const float* Ws2 = (const float*)d_in[13];
  const float* Wn2 = (const float*)d_in[14];
  const float* b2  = (const float*)d_in[15];
  const float* Wc  = (const float*)d_in[16];
  const float* bc  = (const float*)d_in[17];
  float* out = (float*)d_out;

  char* ws = (char*)d_ws;
  const size_t MB = 1u << 20;
  // lifetimes: x16 dead after XW1/XS1; XW1,XS1 dead after recur1;
  // h1 dead after XW2/XS2; so XS2 aliases XS1, h2 aliases XW1.
  u16* x16 = (u16*)(ws + 0);          //  8 MB
  u16* XW1 = (u16*)(ws + 8 * MB);     // 32 MB
  u16* XS1 = (u16*)(ws + 40 * MB);    // 16 MB
  u16* h1  = (u16*)(ws + 56 * MB);    // 16 MB
  u16* XW2 = (u16*)(ws + 72 * MB);    // 64 MB
  u16* XS2 = (u16*)(ws + 40 * MB);    // alias XS1
  u16* h2  = (u16*)(ws + 8 * MB);     // alias XW1
  char* wr = ws + 136 * MB;
  size_t off = 0;
  auto alloc = [&](size_t bytes) { void* p = wr + off; off += (bytes + 255) & ~(size_t)255; return p; };
  u16*   Bxw1 = (u16*)alloc(512 * 128 * 2);
  u16*   Bh1  = (u16*)alloc(512 * 128 * 2);
  float* bw1  = (float*)alloc(512 * 4);
  u16*   Bs1  = (u16*)alloc(256 * 128 * 2);
  u16*   Bn1  = (u16*)alloc(256 * 128 * 2);
  u16*   Bxw2 = (u16*)alloc(1024 * 256 * 2);
  u16*   Bh2  = (u16*)alloc(1024 * 256 * 2);
  float* bw2  = (float*)alloc(1024 * 4);
  u16*   Bs2  = (u16*)alloc(256 * 256 * 2);
  u16*   Bn2  = (u16*)alloc(256 * 256 * 2);

  k_prep_x<<<dim3(N_NODES * IN_F / 4 / 256), dim3(256), 0, stream>>>(x, x16, N_NODES * IN_F / 4);
  k_prep_perm<<<dim3(256), dim3(256), 0, stream>>>(Wi1, Wh1, bi1, bh1, Bxw1, Bh1, bw1, IN_F);
  k_prep_perm<<<dim3(1024), dim3(256), 0, stream>>>(Wi2, Wh2, bi2, bh2, Bxw2, Bh2, bw2, HIDF);
  k_prep_cast<<<dim3(128), dim3(256), 0, stream>>>(Ws1, Wn1, Bs1, Bn1, 256 * 128);
  k_prep_cast<<<dim3(256), dim3(256), 0, stream>>>(Ws2, Wn2, Bs2, Bn2, 256 * 256);

  k_gemm<128, 512><<<dim3(N_NODES / 64, 4), dim3(256), 0, stream>>>(x16, Bxw1, bw1, XW1);
  k_gemm<128, 256><<<dim3(N_NODES / 64, 2), dim3(256), 0, stream>>>(x16, Bs1, b1, XS1);
  k_recur<IN_F><<<dim3(N_NODES / 32), dim3(512), 0, stream>>>(XW1, XS1, nbr, Bh1, Bn1, h1);
  k_gemm<256, 1024><<<dim3(N_NODES / 64, 8), dim3(256), 0, stream>>>(h1, Bxw2, bw2, XW2);
  k_gemm<256, 256><<<dim3(N_NODES / 64, 2), dim3(256), 0, stream>>>(h1, Bs2, b2, XS2);
  k_recur<HIDF><<<dim3(N_NODES / 32), dim3(512), 0, stream>>>(XW2, XS2, nbr, Bh2, Bn2, h2);

  k_pool<<<dim3(N_GRAPHS), dim3(256), 0, stream>>>(h2, Wc, bc, out);
}